// Round 6
// baseline (485.456 us; speedup 1.0000x reference)
//
#include <hip/hip_runtime.h>
#include <math.h>

#define BSZ 4096

typedef __attribute__((ext_vector_type(8))) short bf16x8;
typedef __attribute__((ext_vector_type(4))) float f32x4;

// ST layout (floats): rowZ@0, rowF@262144, rowW@524288 (each [64 part][4096 row])
//                     colZ@786432, colE@1048576, colW@1310720
//                     Tpart@1572864 ([4096 waves][4])
#define ST_ROW 0
#define ST_COL 786432
#define ST_T   1572864
#define ST_FLOATS 1589248

__device__ __forceinline__ unsigned short f2b(float f) {
    unsigned u = __float_as_uint(f);
    u = u + 0x7fffu + ((u >> 16) & 1u);
    return (unsigned short)(u >> 16);
}
__device__ __forceinline__ float b2f(unsigned short s) {
    return __uint_as_float(((unsigned)s) << 16);
}

// ---------------------------------------------------------------------------
// fp32 -> bf16 cast, 4 elems/thread (n multiple of 4)
// ---------------------------------------------------------------------------
__global__ void cast_kernel(const float* __restrict__ x, unsigned short* __restrict__ o, int n) {
    int i = (blockIdx.x * 256 + threadIdx.x) * 4;
    if (i >= n) return;
    float4 v = *(const float4*)(x + i);
    ushort4 r;
    r.x = f2b(v.x); r.y = f2b(v.y); r.z = f2b(v.z); r.w = f2b(v.w);
    *(ushort4*)(o + i) = r;
}

// Combined weight cast into one packed bf16 buffer (compile-time offsets).
__global__ void cast_w_kernel(const float* __restrict__ l1, const float* __restrict__ l2,
                              const float* __restrict__ l3, const float* __restrict__ tl2,
                              const float* __restrict__ isp, const float* __restrict__ ish,
                              const float* __restrict__ tsh, const float* __restrict__ tsp,
                              unsigned short* __restrict__ o) {
    int i = (blockIdx.x * 256 + threadIdx.x) * 4;
    if (i >= 1294336) return;
    const float* src; int off;
    if (i < 1048576)      { src = l1;  off = 0; }
    else if (i < 1179648) { src = l2;  off = 1048576; }
    else if (i < 1212416) { src = l3;  off = 1179648; }
    else if (i < 1228800) { src = tl2; off = 1212416; }
    else if (i < 1245184) { src = isp; off = 1228800; }
    else if (i < 1261568) { src = ish; off = 1245184; }
    else if (i < 1277952) { src = tsh; off = 1261568; }
    else                  { src = tsp; off = 1277952; }
    float4 v = *(const float4*)(src + (i - off));
    ushort4 r;
    r.x = f2b(v.x); r.y = f2b(v.y); r.z = f2b(v.z); r.w = f2b(v.w);
    *(ushort4*)(o + i) = r;
}

// ---------------------------------------------------------------------------
// SIMT GEMM (only for tl1, K=49), bf16 output. A:[M,K] f32, W:[N,K] f32.
// ---------------------------------------------------------------------------
__global__ void gemm_small(const float* __restrict__ A, const float* __restrict__ W,
                           const float* __restrict__ bias, unsigned short* __restrict__ C,
                           int M, int N, int K, int relu) {
    __shared__ float As[16][65];
    __shared__ float Ws[16][65];
    const int tx = threadIdx.x, ty = threadIdx.y;
    const int tid = ty * 16 + tx;
    const int m0 = blockIdx.y * 64, n0 = blockIdx.x * 64;
    float acc[4][4] = {};
    const int lrow = tid >> 2;
    const int lkb = (tid & 3) * 4;
    for (int k0 = 0; k0 < K; k0 += 16) {
#pragma unroll
        for (int u = 0; u < 4; ++u) {
            int k = k0 + lkb + u;
            As[lkb + u][lrow] = (k < K) ? A[(size_t)(m0 + lrow) * K + k] : 0.0f;
            Ws[lkb + u][lrow] = (k < K) ? W[(size_t)(n0 + lrow) * K + k] : 0.0f;
        }
        __syncthreads();
#pragma unroll
        for (int kk = 0; kk < 16; ++kk) {
            float av[4], bv[4];
#pragma unroll
            for (int i = 0; i < 4; ++i) av[i] = As[kk][ty * 4 + i];
#pragma unroll
            for (int j = 0; j < 4; ++j) bv[j] = Ws[kk][tx * 4 + j];
#pragma unroll
            for (int i = 0; i < 4; ++i)
#pragma unroll
                for (int j = 0; j < 4; ++j) acc[i][j] += av[i] * bv[j];
        }
        __syncthreads();
    }
#pragma unroll
    for (int i = 0; i < 4; ++i)
#pragma unroll
        for (int j = 0; j < 4; ++j) {
            int n = n0 + tx * 4 + j;
            float v = acc[i][j] + bias[n];
            if (relu) v = fmaxf(v, 0.0f);
            C[(size_t)(m0 + ty * 4 + i) * N + n] = f2b(v);
        }
}

// ---------------------------------------------------------------------------
// MFMA GEMM body: C = act(A @ W^T + bias). A:[M,K] bf16, W:[N,K] bf16.
// Tile 128x128, 4 waves (2x2 of 64x64), BK=64, 16x16x32 bf16 MFMA.
// LDS XOR-swizzle: LDS[row][cbp] holds global col-block (cbp ^ (row&7)).
// ---------------------------------------------------------------------------
__device__ __forceinline__ void gemm_body(const unsigned short* __restrict__ A,
                                          const unsigned short* __restrict__ W,
                                          const float* __restrict__ bias,
                                          unsigned short* __restrict__ Cb,
                                          float* __restrict__ Cf,
                                          int N, int K, int relu, int bx, int by,
                                          short* As, short* Bs) {
    const int tid = threadIdx.x;
    const int w = tid >> 6, lane = tid & 63, quad = lane >> 4, l15 = lane & 15;
    const int m0 = by * 128, n0 = bx * 128;
    const int rw = (w >> 1) * 64, cw = (w & 1) * 64;
    f32x4 acc[4][4];
#pragma unroll
    for (int i = 0; i < 4; ++i)
#pragma unroll
        for (int j = 0; j < 4; ++j) acc[i][j] = (f32x4){0.f, 0.f, 0.f, 0.f};

    for (int k0 = 0; k0 < K; k0 += 64) {
#pragma unroll
        for (int r = 0; r < 4; ++r) {
            int idx = r * 256 + tid;
            int row = idx >> 3, cbp = idx & 7;
            int col = ((cbp ^ (row & 7)) << 3);
            *(bf16x8*)&As[row * 64 + cbp * 8] = *(const bf16x8*)&A[(size_t)(m0 + row) * K + k0 + col];
            *(bf16x8*)&Bs[row * 64 + cbp * 8] = *(const bf16x8*)&W[(size_t)(n0 + row) * K + k0 + col];
        }
        __syncthreads();
#pragma unroll
        for (int kb = 0; kb < 2; ++kb) {
            bf16x8 af[4], bfr[4];
            int cb = kb * 4 + quad;
#pragma unroll
            for (int i = 0; i < 4; ++i) {
                int row = rw + i * 16 + l15;
                af[i] = *(const bf16x8*)&As[row * 64 + ((cb ^ (row & 7)) << 3)];
            }
#pragma unroll
            for (int j = 0; j < 4; ++j) {
                int row = cw + j * 16 + l15;
                bfr[j] = *(const bf16x8*)&Bs[row * 64 + ((cb ^ (row & 7)) << 3)];
            }
#pragma unroll
            for (int i = 0; i < 4; ++i)
#pragma unroll
                for (int j = 0; j < 4; ++j)
                    acc[i][j] = __builtin_amdgcn_mfma_f32_16x16x32_bf16(af[i], bfr[j], acc[i][j], 0, 0, 0);
        }
        __syncthreads();
    }
    // epilogue: C/D layout col=lane&15 (n), row=quad*4+reg (m)
#pragma unroll
    for (int j = 0; j < 4; ++j) {
        int n = n0 + cw + j * 16 + l15;
        float bv = bias[n];
#pragma unroll
        for (int i = 0; i < 4; ++i) {
#pragma unroll
            for (int r = 0; r < 4; ++r) {
                int m = m0 + rw + i * 16 + quad * 4 + r;
                float v = acc[i][j][r] + bv;
                if (relu) v = fmaxf(v, 0.f);
                if (Cb) Cb[(size_t)m * N + n] = f2b(v);
                if (Cf) Cf[(size_t)m * N + n] = v;
            }
        }
    }
}

__global__ __launch_bounds__(256) void mfma_gemm(const unsigned short* __restrict__ A,
                                                 const unsigned short* __restrict__ W,
                                                 const float* __restrict__ bias,
                                                 unsigned short* __restrict__ Cb,
                                                 float* __restrict__ Cf, int N, int K, int relu) {
    __shared__ alignas(16) short As[128 * 64];
    __shared__ alignas(16) short Bs[128 * 64];
    gemm_body(A, W, bias, Cb, Cf, N, K, relu, blockIdx.x, blockIdx.y, As, Bs);
}

// Batched SS heads: z selects (input, weight, bias, out). N=K=128, fp32 out.
__global__ __launch_bounds__(256) void mfma_heads(const unsigned short* __restrict__ FIb,
                                                  const unsigned short* __restrict__ FTb,
                                                  const unsigned short* __restrict__ Wisp,
                                                  const unsigned short* __restrict__ Wish,
                                                  const unsigned short* __restrict__ Wtsh,
                                                  const unsigned short* __restrict__ Wtsp,
                                                  const float* __restrict__ bisp, const float* __restrict__ bish,
                                                  const float* __restrict__ btsh, const float* __restrict__ btsp,
                                                  float* __restrict__ ISP, float* __restrict__ ISH,
                                                  float* __restrict__ TSH, float* __restrict__ TSP) {
    __shared__ alignas(16) short As[128 * 64];
    __shared__ alignas(16) short Bs[128 * 64];
    int z = blockIdx.z;
    const unsigned short* A = (z < 2) ? FIb : FTb;
    const unsigned short* W = z == 0 ? Wisp : z == 1 ? Wish : z == 2 ? Wtsh : Wtsp;
    const float* b = z == 0 ? bisp : z == 1 ? bish : z == 2 ? btsh : btsp;
    float* C = z == 0 ? ISP : z == 1 ? ISH : z == 2 ? TSH : TSP;
    gemm_body(A, W, b, nullptr, C, 128, 128, 0, 0, blockIdx.y, As, Bs);
}

// ---------------------------------------------------------------------------
// Row-normalize (z-batched, 4 tensors): out bf16. z<2 inputs bf16, else fp32.
// ---------------------------------------------------------------------------
__global__ void rownorm4(const unsigned short* __restrict__ fi, const unsigned short* __restrict__ ft,
                         const float* __restrict__ ish, const float* __restrict__ tsh,
                         unsigned short* __restrict__ fin, unsigned short* __restrict__ ftn,
                         unsigned short* __restrict__ ishn, unsigned short* __restrict__ tshn) {
    int z = blockIdx.y;
    int m = blockIdx.x * 256 + threadIdx.x;
    const unsigned short* sb = (z == 0) ? fi : ft;
    const float* sf = (z == 2) ? ish : tsh;
    unsigned short* dst = z == 0 ? fin : z == 1 ? ftn : z == 2 ? ishn : tshn;
    float ss = 0.f;
    if (z < 2) {
        for (int u = 0; u < 128; u += 8) {
            bf16x8 v = *(const bf16x8*)&sb[(size_t)m * 128 + u];
#pragma unroll
            for (int e = 0; e < 8; ++e) { float f = b2f((unsigned short)v[e]); ss += f * f; }
        }
    } else {
        for (int u = 0; u < 128; u += 4) {
            float4 v = *(const float4*)&sf[(size_t)m * 128 + u];
            ss += v.x * v.x + v.y * v.y + v.z * v.z + v.w * v.w;
        }
    }
    float inv = 1.f / fmaxf(sqrtf(ss), 1e-12f);
    if (z < 2) {
        for (int u = 0; u < 128; u += 8) {
            bf16x8 v = *(const bf16x8*)&sb[(size_t)m * 128 + u];
            ushort4 o0, o1;
            o0.x = f2b(b2f((unsigned short)v[0]) * inv); o0.y = f2b(b2f((unsigned short)v[1]) * inv);
            o0.z = f2b(b2f((unsigned short)v[2]) * inv); o0.w = f2b(b2f((unsigned short)v[3]) * inv);
            o1.x = f2b(b2f((unsigned short)v[4]) * inv); o1.y = f2b(b2f((unsigned short)v[5]) * inv);
            o1.z = f2b(b2f((unsigned short)v[6]) * inv); o1.w = f2b(b2f((unsigned short)v[7]) * inv);
            *(ushort4*)&dst[(size_t)m * 128 + u] = o0;
            *(ushort4*)&dst[(size_t)m * 128 + u + 4] = o1;
        }
    } else {
        for (int u = 0; u < 128; u += 4) {
            float4 v = *(const float4*)&sf[(size_t)m * 128 + u];
            ushort4 o;
            o.x = f2b(v.x * inv); o.y = f2b(v.y * inv); o.z = f2b(v.z * inv); o.w = f2b(v.w * inv);
            *(ushort4*)&dst[(size_t)m * 128 + u] = o;
        }
    }
}

// ---------------------------------------------------------------------------
// Count y==0 -> scal[0]
// ---------------------------------------------------------------------------
__global__ void county_kernel(const int* __restrict__ y, float* __restrict__ scal) {
    __shared__ int red[256];
    int t = threadIdx.x;
    int c = 0;
    for (int i = t; i < BSZ; i += 256) c += (y[i] == 0) ? 1 : 0;
    red[t] = c;
    __syncthreads();
    for (int s = 128; s > 0; s >>= 1) {
        if (t < s) red[t] += red[t + s];
        __syncthreads();
    }
    if (t == 0) scal[0] = (float)red[0];
}

// ---------------------------------------------------------------------------
// MFMA CLIP tile (z=2 merged): S = In @ Tn^T, 128x128 tile/block, BK=64
// staging (32 KB LDS -> 4 blocks/CU). Transpose-reduce epilogue.
// ---------------------------------------------------------------------------
__global__ __launch_bounds__(256) void clip_mfma(const unsigned short* __restrict__ In1,
                                                 const unsigned short* __restrict__ Tn1,
                                                 const unsigned short* __restrict__ In2,
                                                 const unsigned short* __restrict__ Tn2,
                                                 const int* __restrict__ y,
                                                 const float* __restrict__ scale_log1,
                                                 const float* __restrict__ scale_log2,
                                                 float* __restrict__ st1, float* __restrict__ st2) {
    __shared__ alignas(16) short As[128 * 64];
    __shared__ alignas(16) short Bs[128 * 64];
    const int z = blockIdx.z;
    const unsigned short* In = z ? In2 : In1;
    const unsigned short* Tn = z ? Tn2 : Tn1;
    const float* scale_log = z ? scale_log2 : scale_log1;
    float* st = z ? st2 : st1;
    const int tid = threadIdx.x;
    const int w = tid >> 6, lane = tid & 63, quad = lane >> 4, l15 = lane & 15;
    const int bx = blockIdx.x, by = blockIdx.y;
    const int r0 = by * 128, c0 = bx * 128;
    const int rw = (w >> 1) * 64, cw = (w & 1) * 64;
    f32x4 acc[4][4];
#pragma unroll
    for (int i = 0; i < 4; ++i)
#pragma unroll
        for (int j = 0; j < 4; ++j) acc[i][j] = (f32x4){0.f, 0.f, 0.f, 0.f};
    for (int k0 = 0; k0 < 128; k0 += 64) {
#pragma unroll
        for (int r = 0; r < 4; ++r) {
            int idx = r * 256 + tid;
            int row = idx >> 3, cbp = idx & 7;
            int col = ((cbp ^ (row & 7)) << 3);
            *(bf16x8*)&As[row * 64 + cbp * 8] = *(const bf16x8*)&In[(size_t)(r0 + row) * 128 + k0 + col];
            *(bf16x8*)&Bs[row * 64 + cbp * 8] = *(const bf16x8*)&Tn[(size_t)(c0 + row) * 128 + k0 + col];
        }
        __syncthreads();
#pragma unroll
        for (int kb = 0; kb < 2; ++kb) {
            bf16x8 af[4], bfr[4];
            int cb = kb * 4 + quad;
#pragma unroll
            for (int i = 0; i < 4; ++i) {
                int row = rw + i * 16 + l15;
                af[i] = *(const bf16x8*)&As[row * 64 + ((cb ^ (row & 7)) << 3)];
            }
#pragma unroll
            for (int j = 0; j < 4; ++j) {
                int row = cw + j * 16 + l15;
                bfr[j] = *(const bf16x8*)&Bs[row * 64 + ((cb ^ (row & 7)) << 3)];
            }
#pragma unroll
            for (int i = 0; i < 4; ++i)
#pragma unroll
                for (int j = 0; j < 4; ++j)
                    acc[i][j] = __builtin_amdgcn_mfma_f32_16x16x32_bf16(af[i], bfr[j], acc[i][j], 0, 0, 0);
        }
        __syncthreads();
    }

    const float s = expf(scale_log[0]);
    int yrow[4][4]; float mrow[4][4];
    int ycol[4];    float mcol[4];
#pragma unroll
    for (int i = 0; i < 4; ++i)
#pragma unroll
        for (int r = 0; r < 4; ++r) {
            int yy = y[r0 + rw + i * 16 + quad * 4 + r];
            yrow[i][r] = yy; mrow[i][r] = (yy == 0) ? 1.f : 0.f;
        }
#pragma unroll
    for (int j = 0; j < 4; ++j) {
        int yy = y[c0 + cw + j * 16 + l15];
        ycol[j] = yy; mcol[j] = (yy == 0) ? 1.f : 0.f;
    }
    // row stats flattened: idx = i*4+r
    float vZ[16], vF[16], vW[16];
#pragma unroll
    for (int q = 0; q < 16; ++q) { vZ[q] = 0.f; vF[q] = 0.f; vW[q] = 0.f; }
    float cZ[4] = {}, cE[4] = {}, cW[4] = {};
    float aAll = 0.f, aC0 = 0.f, aR0 = 0.f, aRC = 0.f;
#pragma unroll
    for (int i = 0; i < 4; ++i)
#pragma unroll
        for (int r = 0; r < 4; ++r) {
            const int idx = i * 4 + r;
            float mr = mrow[i][r];
            int yr = yrow[i][r];
#pragma unroll
            for (int j = 0; j < 4; ++j) {
                float S = acc[i][j][r];
                float L = s * S;
                float e1 = __expf(L);
                float e2 = __expf(S);
                float msk = (yr == ycol[j]) ? 1.f : 0.f;
                vZ[idx] += e1; vF[idx] += e1 * L; vW[idx] += e1 * msk;
                cZ[j] += e2;   cE[j] += e2 * S;   cW[j] += e2 * msk;
                float tmp = S * mcol[j];
                aAll += S; aC0 += tmp; aR0 += S * mr; aRC += tmp * mr;
            }
        }
    // transpose-reduce row stats over 16 lanes: result for idx lands at l15==idx
#pragma unroll
    for (int b = 8; b >= 1; b >>= 1) {
        const bool hi = (l15 & b) != 0;
#pragma unroll
        for (int j = 0; j < b; ++j) {
            float sZ = hi ? vZ[j] : vZ[j + b];
            float kZ = hi ? vZ[j + b] : vZ[j];
            vZ[j] = kZ + __shfl_xor(sZ, b);
            float sF = hi ? vF[j] : vF[j + b];
            float kF = hi ? vF[j + b] : vF[j];
            vF[j] = kF + __shfl_xor(sF, b);
            float sW = hi ? vW[j] : vW[j + b];
            float kW = hi ? vW[j + b] : vW[j];
            vW[j] = kW + __shfl_xor(sW, b);
        }
    }
    {
        const int p_row = bx * 2 + (cw >> 6);
        int grow = r0 + rw + (l15 >> 2) * 16 + quad * 4 + (l15 & 3);
        int base = ST_ROW + p_row * 4096 + grow;
        st[base]          = vZ[0];
        st[base + 262144] = vF[0];
        st[base + 524288] = vW[0];
    }
    // transpose-reduce col stats over 4 quad groups: result for j lands at quad==j
#pragma unroll
    for (int b = 2; b >= 1; b >>= 1) {
        const int lm = b << 4;  // lane mask: 32 then 16
        const bool hi = (lane & lm) != 0;
#pragma unroll
        for (int j = 0; j < b; ++j) {
            float sZ = hi ? cZ[j] : cZ[j + b];
            float kZ = hi ? cZ[j + b] : cZ[j];
            cZ[j] = kZ + __shfl_xor(sZ, lm);
            float sE = hi ? cE[j] : cE[j + b];
            float kE = hi ? cE[j + b] : cE[j];
            cE[j] = kE + __shfl_xor(sE, lm);
            float sW = hi ? cW[j] : cW[j + b];
            float kW = hi ? cW[j + b] : cW[j];
            cW[j] = kW + __shfl_xor(sW, lm);
        }
    }
    {
        const int p_col = by * 2 + (rw >> 6);
        int gcol = c0 + cw + quad * 16 + l15;
        int base = ST_COL + p_col * 4096 + gcol;
        st[base]          = cZ[0];
        st[base + 262144] = cE[0];
        st[base + 524288] = cW[0];
    }
    // T scalars: full-wave reduce, per-wave store
#pragma unroll
    for (int m = 1; m < 64; m <<= 1) {
        aAll += __shfl_xor(aAll, m); aC0 += __shfl_xor(aC0, m);
        aR0 += __shfl_xor(aR0, m);   aRC += __shfl_xor(aRC, m);
    }
    if (lane == 0) {
        int wg = (by * 32 + bx) * 4 + w;
        float T00 = aRC, T01 = aR0 - aRC, T10 = aC0 - aRC, T11 = aAll - aR0 - aC0 + aRC;
        st[ST_T + wg * 4 + 0] = T00;
        st[ST_T + wg * 4 + 1] = T01;
        st[ST_T + wg * 4 + 2] = T10;
        st[ST_T + wg * 4 + 3] = T11;
    }
}

// ---------------------------------------------------------------------------
// CLIP finalize: one WAVE per row (lane = partial index). grid (1024, 2),
// block = 256 = 4 rows. Per-row v -> RV (plain store). Block (0,z) also
// reduces the T-partials into TT[z*4 .. z*4+3].
// ---------------------------------------------------------------------------
__global__ __launch_bounds__(256) void clip_finalize(const float* __restrict__ st1,
                                                     const float* __restrict__ st2,
                                                     const int* __restrict__ y,
                                                     const float* __restrict__ scal,
                                                     float* __restrict__ RV,
                                                     float* __restrict__ TT) {
    const int z = blockIdx.y;
    const float* st = z ? st2 : st1;
    const int tid = threadIdx.x;
    const int lane = tid & 63;
    const int k = blockIdx.x * 4 + (tid >> 6);
    const float Bf = (float)BSZ;
    const int base = lane * 4096 + k;
    float Z1 = st[ST_ROW + base];
    float F1 = st[ST_ROW + 262144 + base];
    float W1 = st[ST_ROW + 524288 + base];
    float Z2 = st[ST_COL + base];
    float E2 = st[ST_COL + 262144 + base];
    float W2 = st[ST_COL + 524288 + base];
#pragma unroll
    for (int m = 1; m < 64; m <<= 1) {
        Z1 += __shfl_xor(Z1, m); F1 += __shfl_xor(F1, m); W1 += __shfl_xor(W1, m);
        Z2 += __shfl_xor(Z2, m); E2 += __shfl_xor(E2, m); W2 += __shfl_xor(W2, m);
    }
    if (lane == 0) {
        float n0 = scal[0];
        int yk = y[k];
        float n = (yk == 0) ? n0 : (Bf - n0);
        float a = 1.0f / n;
        float ea = expf(a);
        float denom = n * ea + (Bf - n);
        float q_s = ea / denom, q_d = 1.0f / denom;
        float ld = logf(denom);
        float lq_s = a - ld, lq_d = -ld;
        float Qlq = n * q_s * lq_s + (Bf - n) * q_d * lq_d;
        float term_r = Qlq + F1 / Z1 - lq_d - (lq_s - lq_d) * (W1 / Z1);
        float term_c = Qlq + E2 / Z2 - lq_d - (lq_s - lq_d) * (W2 / Z2);
        RV[(size_t)z * BSZ + k] = (term_r + term_c) / (4.0f * Bf);
    }
    if (blockIdx.x == 0) {
        __shared__ float4 tred[256];
        const float4* tp = (const float4*)&st[ST_T];
        float4 acc = {0.f, 0.f, 0.f, 0.f};
        for (int u = tid; u < 4096; u += 256) {
            float4 t4 = tp[u];
            acc.x += t4.x; acc.y += t4.y; acc.z += t4.z; acc.w += t4.w;
        }
        tred[tid] = acc;
        __syncthreads();
        for (int ss2 = 128; ss2 > 0; ss2 >>= 1) {
            if (tid < ss2) {
                tred[tid].x += tred[tid + ss2].x; tred[tid].y += tred[tid + ss2].y;
                tred[tid].z += tred[tid + ss2].z; tred[tid].w += tred[tid + ss2].w;
            }
            __syncthreads();
        }
        if (tid == 0) {
            TT[z * 4 + 0] = tred[0].x; TT[z * 4 + 1] = tred[0].y;
            TT[z * 4 + 2] = tred[0].z; TT[z * 4 + 3] = tred[0].w;
        }
    }
}

// ---------------------------------------------------------------------------
// gram_splitk: G_mat = X^T X (128x128, K=4096) split-K in 64-row chunks, fp32.
// ||A@B^T||_F^2 = sum (A^T A)∘(B^T B). grid (64, 4). Partials to GP.
// ---------------------------------------------------------------------------
__global__ __launch_bounds__(256) void gram_splitk(const float* __restrict__ isp,
                                                   const float* __restrict__ ish,
                                                   const float* __restrict__ tsp,
                                                   const float* __restrict__ tsh,
                                                   float* __restrict__ GP) {
    __shared__ alignas(16) float As2[64][128];
    const int mat = blockIdx.y, chunk = blockIdx.x;
    const float* A = mat == 0 ? isp : mat == 1 ? ish : mat == 2 ? tsp : tsh;
    const int tid = threadIdx.x;
    const int m0 = chunk * 64;
#pragma unroll
    for (int r = 0; r < 8; ++r) {
        int idx = r * 256 + tid;
        int row = idx >> 5, c4 = (idx & 31) * 4;
        *(float4*)&As2[row][c4] = *(const float4*)&A[(size_t)(m0 + row) * 128 + c4];
    }
    __syncthreads();
    const int ty = tid >> 4, tx = tid & 15;
    float acc[8][8] = {};
    for (int k = 0; k < 64; ++k) {
        float av[8], bv[8];
        *(float4*)&av[0] = *(const float4*)&As2[k][ty * 8];
        *(float4*)&av[4] = *(const float4*)&As2[k][ty * 8 + 4];
        *(float4*)&bv[0] = *(const float4*)&As2[k][tx * 8];
        *(float4*)&bv[4] = *(const float4*)&As2[k][tx * 8 + 4];
#pragma unroll
        for (int i = 0; i < 8; ++i)
#pragma unroll
            for (int j = 0; j < 8; ++j) acc[i][j] += av[i] * bv[j];
    }
    float* Gp = GP + ((size_t)(mat * 64 + chunk) << 14);
#pragma unroll
    for (int i = 0; i < 8; ++i) {
        *(float4*)&Gp[(ty * 8 + i) * 128 + tx * 8]     = *(float4*)&acc[i][0];
        *(float4*)&Gp[(ty * 8 + i) * 128 + tx * 8 + 4] = *(float4*)&acc[i][4];
    }
}

// frob_combine: per entry sum 64 K-partials of each Gram in the pair,
// multiply, reduce -> scal[3+z]. z=0: (ISP,ISH), z=1: (TSP,TSH).
__global__ void frob_combine(const float* __restrict__ GP, float* __restrict__ scal) {
    __shared__ float red[256];
    const int z = blockIdx.y;
    const int tid = threadIdx.x;
    int u = blockIdx.x * 1024 + tid * 4;
    float4 ga = {0.f, 0.f, 0.f, 0.f};
    float4 gb = {0.f, 0.f, 0.f, 0.f};
    const size_t baseA = ((size_t)(2 * z) * 64) << 14;
    const size_t baseB = ((size_t)(2 * z + 1) * 64) << 14;
    for (int c = 0; c < 64; ++c) {
        float4 va = *(const float4*)&GP[baseA + ((size_t)c << 14) + u];
        float4 vb = *(const float4*)&GP[baseB + ((size_t)c << 14) + u];
        ga.x += va.x; ga.y += va.y; ga.z += va.z; ga.w += va.w;
        gb.x += vb.x; gb.y += vb.y; gb.z += vb.z; gb.w += vb.w;
    }
    red[tid] = ga.x * gb.x + ga.y * gb.y + ga.z * gb.z + ga.w * gb.w;
    __syncthreads();
    for (int ss = 128; ss > 0; ss >>= 1) {
        if (tid < ss) red[tid] += red[tid + ss];
        __syncthreads();
    }
    if (tid == 0) atomicAdd(&scal[3 + z], red[0]);
}

// ---------------------------------------------------------------------------
// Scalar heads (z-batched): out[1 + z*BSZ + m] = dot(X[m], w) + b
// ---------------------------------------------------------------------------
__global__ void head4(const float* __restrict__ isp, const float* __restrict__ ish,
                      const float* __restrict__ tsp, const float* __restrict__ tsh,
                      const float* __restrict__ c1w, const float* __restrict__ c2w,
                      const float* __restrict__ c4w, const float* __restrict__ c3w,
                      const float* __restrict__ c1b, const float* __restrict__ c2b,
                      const float* __restrict__ c4b, const float* __restrict__ c3b,
                      float* __restrict__ out) {
    int z = blockIdx.y;
    const float* X = z == 0 ? isp : z == 1 ? ish : z == 2 ? tsp : tsh;
    const float* w = z == 0 ? c1w : z == 1 ? c2w : z == 2 ? c4w : c3w;
    const float* b = z == 0 ? c1b : z == 1 ? c2b : z == 2 ? c4b : c3b;
    int m = blockIdx.x * 256 + threadIdx.x;
    const float4* xp = (const float4*)(X + (size_t)m * 128);
    const float4* wp = (const float4*)w;
    float acc = 0.0f;
#pragma unroll
    for (int u = 0; u < 32; ++u) {
        float4 av = xp[u], cv = wp[u];
        acc += av.x * cv.x + av.y * cv.y + av.z * cv.z + av.w * cv.w;
    }
    out[1 + (size_t)z * BSZ + m] = acc + b[0];
}

// ---------------------------------------------------------------------------
// Final: sum RV per z + T tails + gram terms -> out[0]
// ---------------------------------------------------------------------------
__global__ void final_kernel(const float* __restrict__ RV, const float* __restrict__ scal,
                             const float* __restrict__ sl1, const float* __restrict__ sl2,
                             float* __restrict__ out) {
    __shared__ float red0[256], red1[256];
    int tid = threadIdx.x;
    float s0 = 0.f, s1 = 0.f;
    for (int u = tid; u < BSZ; u += 256) { s0 += RV[u]; s1 += RV[BSZ + u]; }
    red0[tid] = s0; red1[tid] = s1;
    __syncthreads();
    for (int ss = 128; ss > 0; ss >>= 1) {
        if (tid < ss) { red0[tid] += red0[tid + ss]; red1[tid] += red1[tid + ss]; }
        __syncthreads();
    }
    if (tid == 0) {
        const float Bf = (float)BSZ;
        float n0 = scal[0], n1 = Bf - n0;
        float e0 = expf(1.f / n0), e1 = expf(1.f / n1);
        float d0 = n0 * e0 + (Bf - n0), d1 = n1 * e1 + (Bf - n1);
        float qs0 = e0 / d0, qd0 = 1.f / d0, qs1 = e1 / d1, qd1 = 1.f / d1;
        float loss_z[2];
        for (int z = 0; z < 2; ++z) {
            float T00 = scal[8 + z * 4 + 0], T01 = scal[8 + z * 4 + 1];
            float T10 = scal[8 + z * 4 + 2], T11 = scal[8 + z * 4 + 3];
            float QS1 = qd0 * (T00 + T01) + (qs0 - qd0) * T00 + qd1 * (T10 + T11) + (qs1 - qd1) * T11;
            float QS2 = qd0 * (T00 + T10) + (qs0 - qd0) * T00 + qd1 * (T01 + T11) + (qs1 - qd1) * T11;
            float s = expf(z ? sl2[0] : sl1[0]);
            loss_z[z] = (z ? red1[0] : red0[0]) + (-s * QS1 - QS2) / (4.0f * Bf);
        }
        float loss_sp = 0.5f * (sqrtf(scal[4]) + sqrtf(scal[3]));
        out[0] = (loss_sp + loss_z[1] + loss_z[0]) / 3.0f;
    }
}

// ---------------------------------------------------------------------------
extern "C" void kernel_launch(void* const* d_in, const int* in_sizes, int n_in,
                              void* d_out, int out_size, void* d_ws, size_t ws_size,
                              hipStream_t stream) {
    const float* i_in  = (const float*)d_in[0];
    const float* t_in  = (const float*)d_in[1];
    const int*   y     = (const int*)d_in[2];
    const float* l1_w  = (const float*)d_in[3];
    const float* l1_b  = (const float*)d_in[4];
    const float* l2_w  = (const float*)d_in[5];
    const float* l2_b  = (const float*)d_in[6];
    const float* l3_w  = (const float*)d_in[7];
    const float* l3_b  = (const float*)d_in[8];
    const float* tl1_w = (const float*)d_in[9];
    const float* tl1_b = (const float*)d_in[10];
    const float* tl2_w = (const float*)d_in[11];
    const float* tl2_b = (const float*)d_in[12];
    const float* isp_w = (const float*)d_in[13];
    const float* isp_b = (const float*)d_in[14];
    const float* ish_w = (const float*)d_in[15];
    const float* ish_b = (const float*)d_in[16];
    const float* tsh_w = (const float*)d_in[17];
    const float* tsh_b = (const float*)d_in[18];
    const float* tsp_w = (const float*)d_in[19];
    const float* tsp_b = (const float*)d_in[20];
    const float* c1_w  = (const float*)d_in[21];
    const float* c1_b  = (const float*)d_in[22];
    const float* c2_w  = (const float*)d_in[23];
    const float* c2_b  = (const float*)d_in[24];
    const float* c3_w  = (const float*)d_in[25];
    const float* c3_b  = (const float*)d_in[26];
    const float* c4_w  = (const float*)d_in[27];
    const float* c4_b  = (const float*)d_in[28];
    const float* scale1 = (const float*)d_in[29];
    const float* scale2 = (const float*)d_in[30];

    float* ws = (float*)d_ws;
    // zeroed fp32 region: SCAL only (scal[3],[4] are frob atomic targets;
    // scal[0]=n0 county; scal[8..15]=T sums, plain stores)
    float* SCAL = ws;                       // 64
    float* RV   = ws + 64;                  // 2*4096 per-row clip terms
    // fp32 work buffers
    float* ISP  = RV + 2 * BSZ;
    float* ISH  = ISP + (size_t)BSZ * 128;
    float* TSP  = ISH + (size_t)BSZ * 128;
    float* TSH  = TSP + (size_t)BSZ * 128;
    // bf16 buffers
    unsigned short* IB   = (unsigned short*)(TSH + (size_t)BSZ * 128);
    unsigned short* WB   = IB + (size_t)BSZ * 2048;      // 1294336
    unsigned short* FI1B = WB + 1294336;                 // 4096*512
    unsigned short* FI2B = FI1B + (size_t)BSZ * 512;     // 4096*256
    unsigned short* FIB  = FI2B + (size_t)BSZ * 256;     // 4096*128
    unsigned short* FT1B = FIB + (size_t)BSZ * 128;
    unsigned short* FTB  = FT1B + (size_t)BSZ * 128;
    unsigned short* FINB = FTB + (size_t)BSZ * 128;
    unsigned short* FTNB = FINB + (size_t)BSZ * 128;
    unsigned short* ISHN = FTNB + (size_t)BSZ * 128;
    unsigned short* TSHN = ISHN + (size_t)BSZ * 128;
    // ST partial buffers ALIAS IB (16.8 MB): IB fully consumed by the L1
    // mfma_gemm before clip_mfma runs (stream order).
    float* ST1 = (float*)IB;                 // 1589248 floats
    float* ST2 = ST1 + ST_FLOATS;
    // GP aliases the same region: clip_finalize fully consumes ST (incl. T
    // partials -> SCAL[8..15]) before gram_splitk runs (stream order).
    float* GP = (float*)IB;

    float* out = (float*)d_out;

    hipMemsetAsync(d_ws, 0, 64 * sizeof(float), stream);
    county_kernel<<<1, 256, 0, stream>>>(y, SCAL);
    cast_kernel<<<8192, 256, 0, stream>>>(i_in, IB, BSZ * 2048);
    cast_w_kernel<<<1264, 256, 0, stream>>>(l1_w, l2_w, l3_w, tl2_w, isp_w, ish_w, tsh_w, tsp_w, WB);
    gemm_small<<<dim3(2, 64), dim3(16, 16), 0, stream>>>(t_in, tl1_w, tl1_b, FT1B, BSZ, 128, 49, 1);

    mfma_gemm<<<dim3(4, 32), 256, 0, stream>>>(IB, WB, l1_b, FI1B, nullptr, 512, 2048, 1);
    mfma_gemm<<<dim3(2, 32), 256, 0, stream>>>(FI1B, WB + 1048576, l2_b, FI2B, nullptr, 256, 512, 1);
    mfma_gemm<<<dim3(1, 32), 256, 0, stream>>>(FI2B, WB + 1179648, l3_b, FIB, nullptr, 128, 256, 0);
    mfma_gemm<<<dim3(1, 32), 256, 0, stream>>>(FT1B, WB + 1212416, tl2_b, FTB, nullptr, 128, 128, 0);
    mfma_heads<<<dim3(1, 32, 4), 256, 0, stream>>>(FIB, FTB, WB + 1228800, WB + 1245184, WB + 1261568,
                                                   WB + 1277952, isp_b, ish_b, tsh_b, tsp_b,
                                                   ISP, ISH, TSH, TSP);
    rownorm4<<<dim3(16, 4), 256, 0, stream>>>(FIB, FTB, ISH, TSH, FINB, FTNB, ISHN, TSHN);

    clip_mfma<<<dim3(32, 32, 2), 256, 0, stream>>>(FINB, FTNB, ISHN, TSHN, y, scale1, scale2, ST1, ST2);
    clip_finalize<<<dim3(1024, 2), 256, 0, stream>>>(ST1, ST2, y, SCAL, RV, &SCAL[8]);

    gram_splitk<<<dim3(64, 4), 256, 0, stream>>>(ISP, ISH, TSP, TSH, GP);
    frob_combine<<<dim3(16, 2), 256, 0, stream>>>(GP, SCAL);
    head4<<<dim3(16, 4), 256, 0, stream>>>(ISP, ISH, TSP, TSH, c1_w, c2_w, c4_w, c3_w,
                                           c1_b, c2_b, c4_b, c3_b, out);
    final_kernel<<<1, 256, 0, stream>>>(RV, SCAL, scale1, scale2, out);
}

// Round 7
// 356.029 us; speedup vs baseline: 1.3635x; 1.3635x over previous
//
#include <hip/hip_runtime.h>
#include <math.h>

#define BSZ 4096

typedef __attribute__((ext_vector_type(8))) short bf16x8;
typedef __attribute__((ext_vector_type(4))) float f32x4;

// ST layout (floats): rowZ@0, rowF@262144, rowW@524288 (each [64 part][4096 row])
//                     colZ@786432, colE@1048576, colW@1310720
//                     Tpart@1572864 ([4096 waves][4])
#define ST_ROW 0
#define ST_COL 786432
#define ST_T   1572864
#define ST_FLOATS 1589248

__device__ __forceinline__ unsigned short f2b(float f) {
    unsigned u = __float_as_uint(f);
    u = u + 0x7fffu + ((u >> 16) & 1u);
    return (unsigned short)(u >> 16);
}
__device__ __forceinline__ float b2f(unsigned short s) {
    return __uint_as_float(((unsigned)s) << 16);
}

// ---------------------------------------------------------------------------
// Merged cast: i (8.4M) + all weights (1.29M) -> contiguous bf16 IB|WB.
// ---------------------------------------------------------------------------
__global__ void cast_all(const float* __restrict__ i_in,
                         const float* __restrict__ l1, const float* __restrict__ l2,
                         const float* __restrict__ l3, const float* __restrict__ tl2,
                         const float* __restrict__ isp, const float* __restrict__ ish,
                         const float* __restrict__ tsh, const float* __restrict__ tsp,
                         unsigned short* __restrict__ o) {
    int i = (blockIdx.x * 256 + threadIdx.x) * 4;
    if (i >= 9682944) return;
    const float* src; int off;
    if (i < 8388608)      { src = i_in; off = 0; }
    else if (i < 9437184) { src = l1;  off = 8388608; }
    else if (i < 9568256) { src = l2;  off = 9437184; }
    else if (i < 9601024) { src = l3;  off = 9568256; }
    else if (i < 9617408) { src = tl2; off = 9601024; }
    else if (i < 9633792) { src = isp; off = 9617408; }
    else if (i < 9650176) { src = ish; off = 9633792; }
    else if (i < 9666560) { src = tsh; off = 9650176; }
    else                  { src = tsp; off = 9666560; }
    float4 v = *(const float4*)(src + (i - off));
    ushort4 r;
    r.x = f2b(v.x); r.y = f2b(v.y); r.z = f2b(v.z); r.w = f2b(v.w);
    *(ushort4*)(o + i) = r;
}

// ---------------------------------------------------------------------------
// SIMT GEMM (only for tl1, K=49), bf16 output. A:[M,K] f32, W:[N,K] f32.
// ---------------------------------------------------------------------------
__global__ void gemm_small(const float* __restrict__ A, const float* __restrict__ W,
                           const float* __restrict__ bias, unsigned short* __restrict__ C,
                           int M, int N, int K, int relu) {
    __shared__ float As[16][65];
    __shared__ float Ws[16][65];
    const int tx = threadIdx.x, ty = threadIdx.y;
    const int tid = ty * 16 + tx;
    const int m0 = blockIdx.y * 64, n0 = blockIdx.x * 64;
    float acc[4][4] = {};
    const int lrow = tid >> 2;
    const int lkb = (tid & 3) * 4;
    for (int k0 = 0; k0 < K; k0 += 16) {
#pragma unroll
        for (int u = 0; u < 4; ++u) {
            int k = k0 + lkb + u;
            As[lkb + u][lrow] = (k < K) ? A[(size_t)(m0 + lrow) * K + k] : 0.0f;
            Ws[lkb + u][lrow] = (k < K) ? W[(size_t)(n0 + lrow) * K + k] : 0.0f;
        }
        __syncthreads();
#pragma unroll
        for (int kk = 0; kk < 16; ++kk) {
            float av[4], bv[4];
#pragma unroll
            for (int i = 0; i < 4; ++i) av[i] = As[kk][ty * 4 + i];
#pragma unroll
            for (int j = 0; j < 4; ++j) bv[j] = Ws[kk][tx * 4 + j];
#pragma unroll
            for (int i = 0; i < 4; ++i)
#pragma unroll
                for (int j = 0; j < 4; ++j) acc[i][j] += av[i] * bv[j];
        }
        __syncthreads();
    }
#pragma unroll
    for (int i = 0; i < 4; ++i)
#pragma unroll
        for (int j = 0; j < 4; ++j) {
            int n = n0 + tx * 4 + j;
            float v = acc[i][j] + bias[n];
            if (relu) v = fmaxf(v, 0.0f);
            C[(size_t)(m0 + ty * 4 + i) * N + n] = f2b(v);
        }
}

// ---------------------------------------------------------------------------
// MFMA GEMM body: C = act(A @ W^T + bias). Tile 128x128, 4 waves, BK=64.
// ---------------------------------------------------------------------------
__device__ __forceinline__ void gemm_body(const unsigned short* __restrict__ A,
                                          const unsigned short* __restrict__ W,
                                          const float* __restrict__ bias,
                                          unsigned short* __restrict__ Cb,
                                          float* __restrict__ Cf,
                                          int N, int K, int relu, int bx, int by,
                                          short* As, short* Bs) {
    const int tid = threadIdx.x;
    const int w = tid >> 6, lane = tid & 63, quad = lane >> 4, l15 = lane & 15;
    const int m0 = by * 128, n0 = bx * 128;
    const int rw = (w >> 1) * 64, cw = (w & 1) * 64;
    f32x4 acc[4][4];
#pragma unroll
    for (int i = 0; i < 4; ++i)
#pragma unroll
        for (int j = 0; j < 4; ++j) acc[i][j] = (f32x4){0.f, 0.f, 0.f, 0.f};

    for (int k0 = 0; k0 < K; k0 += 64) {
#pragma unroll
        for (int r = 0; r < 4; ++r) {
            int idx = r * 256 + tid;
            int row = idx >> 3, cbp = idx & 7;
            int col = ((cbp ^ (row & 7)) << 3);
            *(bf16x8*)&As[row * 64 + cbp * 8] = *(const bf16x8*)&A[(size_t)(m0 + row) * K + k0 + col];
            *(bf16x8*)&Bs[row * 64 + cbp * 8] = *(const bf16x8*)&W[(size_t)(n0 + row) * K + k0 + col];
        }
        __syncthreads();
#pragma unroll
        for (int kb = 0; kb < 2; ++kb) {
            bf16x8 af[4], bfr[4];
            int cb = kb * 4 + quad;
#pragma unroll
            for (int i = 0; i < 4; ++i) {
                int row = rw + i * 16 + l15;
                af[i] = *(const bf16x8*)&As[row * 64 + ((cb ^ (row & 7)) << 3)];
            }
#pragma unroll
            for (int j = 0; j < 4; ++j) {
                int row = cw + j * 16 + l15;
                bfr[j] = *(const bf16x8*)&Bs[row * 64 + ((cb ^ (row & 7)) << 3)];
            }
#pragma unroll
            for (int i = 0; i < 4; ++i)
#pragma unroll
                for (int j = 0; j < 4; ++j)
                    acc[i][j] = __builtin_amdgcn_mfma_f32_16x16x32_bf16(af[i], bfr[j], acc[i][j], 0, 0, 0);
        }
        __syncthreads();
    }
#pragma unroll
    for (int j = 0; j < 4; ++j) {
        int n = n0 + cw + j * 16 + l15;
        float bv = bias[n];
#pragma unroll
        for (int i = 0; i < 4; ++i) {
#pragma unroll
            for (int r = 0; r < 4; ++r) {
                int m = m0 + rw + i * 16 + quad * 4 + r;
                float v = acc[i][j][r] + bv;
                if (relu) v = fmaxf(v, 0.f);
                if (Cb) Cb[(size_t)m * N + n] = f2b(v);
                if (Cf) Cf[(size_t)m * N + n] = v;
            }
        }
    }
}

__global__ __launch_bounds__(256) void mfma_gemm(const unsigned short* __restrict__ A,
                                                 const unsigned short* __restrict__ W,
                                                 const float* __restrict__ bias,
                                                 unsigned short* __restrict__ Cb,
                                                 float* __restrict__ Cf, int N, int K, int relu) {
    __shared__ alignas(16) short As[128 * 64];
    __shared__ alignas(16) short Bs[128 * 64];
    gemm_body(A, W, bias, Cb, Cf, N, K, relu, blockIdx.x, blockIdx.y, As, Bs);
}

// Merged chain tails: z=0 -> FI2B @ l3 -> FIB (K=256); z=1 -> FT1B @ tl2 -> FTB (K=128)
__global__ __launch_bounds__(256) void gemm34(const unsigned short* __restrict__ FI2B,
                                              const unsigned short* __restrict__ FT1B,
                                              const unsigned short* __restrict__ WB,
                                              const float* __restrict__ l3_b,
                                              const float* __restrict__ tl2_b,
                                              unsigned short* __restrict__ FIB,
                                              unsigned short* __restrict__ FTB) {
    __shared__ alignas(16) short As[128 * 64];
    __shared__ alignas(16) short Bs[128 * 64];
    if (blockIdx.z == 0)
        gemm_body(FI2B, WB + 1179648, l3_b, FIB, nullptr, 128, 256, 0, 0, blockIdx.y, As, Bs);
    else
        gemm_body(FT1B, WB + 1212416, tl2_b, FTB, nullptr, 128, 128, 0, 0, blockIdx.y, As, Bs);
}

// Batched SS heads: z selects (input, weight, bias, out). N=K=128, fp32 out.
__global__ __launch_bounds__(256) void mfma_heads(const unsigned short* __restrict__ FIb,
                                                  const unsigned short* __restrict__ FTb,
                                                  const unsigned short* __restrict__ Wisp,
                                                  const unsigned short* __restrict__ Wish,
                                                  const unsigned short* __restrict__ Wtsh,
                                                  const unsigned short* __restrict__ Wtsp,
                                                  const float* __restrict__ bisp, const float* __restrict__ bish,
                                                  const float* __restrict__ btsh, const float* __restrict__ btsp,
                                                  float* __restrict__ ISP, float* __restrict__ ISH,
                                                  float* __restrict__ TSH, float* __restrict__ TSP) {
    __shared__ alignas(16) short As[128 * 64];
    __shared__ alignas(16) short Bs[128 * 64];
    int z = blockIdx.z;
    const unsigned short* A = (z < 2) ? FIb : FTb;
    const unsigned short* W = z == 0 ? Wisp : z == 1 ? Wish : z == 2 ? Wtsh : Wtsp;
    const float* b = z == 0 ? bisp : z == 1 ? bish : z == 2 ? btsh : btsp;
    float* C = z == 0 ? ISP : z == 1 ? ISH : z == 2 ? TSH : TSP;
    gemm_body(A, W, b, nullptr, C, 128, 128, 0, 0, blockIdx.y, As, Bs);
}

// ---------------------------------------------------------------------------
// Row-normalize (z-batched, 4 tensors): out bf16. z<2 inputs bf16, else fp32.
// ---------------------------------------------------------------------------
__global__ void rownorm4(const unsigned short* __restrict__ fi, const unsigned short* __restrict__ ft,
                         const float* __restrict__ ish, const float* __restrict__ tsh,
                         unsigned short* __restrict__ fin, unsigned short* __restrict__ ftn,
                         unsigned short* __restrict__ ishn, unsigned short* __restrict__ tshn) {
    int z = blockIdx.y;
    int m = blockIdx.x * 256 + threadIdx.x;
    const unsigned short* sb = (z == 0) ? fi : ft;
    const float* sf = (z == 2) ? ish : tsh;
    unsigned short* dst = z == 0 ? fin : z == 1 ? ftn : z == 2 ? ishn : tshn;
    float ss = 0.f;
    if (z < 2) {
        for (int u = 0; u < 128; u += 8) {
            bf16x8 v = *(const bf16x8*)&sb[(size_t)m * 128 + u];
#pragma unroll
            for (int e = 0; e < 8; ++e) { float f = b2f((unsigned short)v[e]); ss += f * f; }
        }
    } else {
        for (int u = 0; u < 128; u += 4) {
            float4 v = *(const float4*)&sf[(size_t)m * 128 + u];
            ss += v.x * v.x + v.y * v.y + v.z * v.z + v.w * v.w;
        }
    }
    float inv = 1.f / fmaxf(sqrtf(ss), 1e-12f);
    if (z < 2) {
        for (int u = 0; u < 128; u += 8) {
            bf16x8 v = *(const bf16x8*)&sb[(size_t)m * 128 + u];
            ushort4 o0, o1;
            o0.x = f2b(b2f((unsigned short)v[0]) * inv); o0.y = f2b(b2f((unsigned short)v[1]) * inv);
            o0.z = f2b(b2f((unsigned short)v[2]) * inv); o0.w = f2b(b2f((unsigned short)v[3]) * inv);
            o1.x = f2b(b2f((unsigned short)v[4]) * inv); o1.y = f2b(b2f((unsigned short)v[5]) * inv);
            o1.z = f2b(b2f((unsigned short)v[6]) * inv); o1.w = f2b(b2f((unsigned short)v[7]) * inv);
            *(ushort4*)&dst[(size_t)m * 128 + u] = o0;
            *(ushort4*)&dst[(size_t)m * 128 + u + 4] = o1;
        }
    } else {
        for (int u = 0; u < 128; u += 4) {
            float4 v = *(const float4*)&sf[(size_t)m * 128 + u];
            ushort4 o;
            o.x = f2b(v.x * inv); o.y = f2b(v.y * inv); o.z = f2b(v.z * inv); o.w = f2b(v.w * inv);
            *(ushort4*)&dst[(size_t)m * 128 + u] = o;
        }
    }
}

// ---------------------------------------------------------------------------
// MFMA CLIP tile (z=2 merged): BK=64 staging (32 KB LDS), R5 butterfly
// epilogue (REVERTED from R6 transpose-reduce: that blew VGPR 124->168 and
// collapsed occupancy to ~1 wave/SIMD -> 4.4x regression).
// ---------------------------------------------------------------------------
__global__ __launch_bounds__(256) void clip_mfma(const unsigned short* __restrict__ In1,
                                                 const unsigned short* __restrict__ Tn1,
                                                 const unsigned short* __restrict__ In2,
                                                 const unsigned short* __restrict__ Tn2,
                                                 const int* __restrict__ y,
                                                 const float* __restrict__ scale_log1,
                                                 const float* __restrict__ scale_log2,
                                                 float* __restrict__ st1, float* __restrict__ st2) {
    __shared__ alignas(16) short As[128 * 64];
    __shared__ alignas(16) short Bs[128 * 64];
    const int z = blockIdx.z;
    const unsigned short* In = z ? In2 : In1;
    const unsigned short* Tn = z ? Tn2 : Tn1;
    const float* scale_log = z ? scale_log2 : scale_log1;
    float* st = z ? st2 : st1;
    const int tid = threadIdx.x;
    const int w = tid >> 6, lane = tid & 63, quad = lane >> 4, l15 = lane & 15;
    const int bx = blockIdx.x, by = blockIdx.y;
    const int r0 = by * 128, c0 = bx * 128;
    const int rw = (w >> 1) * 64, cw = (w & 1) * 64;
    f32x4 acc[4][4];
#pragma unroll
    for (int i = 0; i < 4; ++i)
#pragma unroll
        for (int j = 0; j < 4; ++j) acc[i][j] = (f32x4){0.f, 0.f, 0.f, 0.f};
    for (int k0 = 0; k0 < 128; k0 += 64) {
#pragma unroll
        for (int r = 0; r < 4; ++r) {
            int idx = r * 256 + tid;
            int row = idx >> 3, cbp = idx & 7;
            int col = ((cbp ^ (row & 7)) << 3);
            *(bf16x8*)&As[row * 64 + cbp * 8] = *(const bf16x8*)&In[(size_t)(r0 + row) * 128 + k0 + col];
            *(bf16x8*)&Bs[row * 64 + cbp * 8] = *(const bf16x8*)&Tn[(size_t)(c0 + row) * 128 + k0 + col];
        }
        __syncthreads();
#pragma unroll
        for (int kb = 0; kb < 2; ++kb) {
            bf16x8 af[4], bfr[4];
            int cb = kb * 4 + quad;
#pragma unroll
            for (int i = 0; i < 4; ++i) {
                int row = rw + i * 16 + l15;
                af[i] = *(const bf16x8*)&As[row * 64 + ((cb ^ (row & 7)) << 3)];
            }
#pragma unroll
            for (int j = 0; j < 4; ++j) {
                int row = cw + j * 16 + l15;
                bfr[j] = *(const bf16x8*)&Bs[row * 64 + ((cb ^ (row & 7)) << 3)];
            }
#pragma unroll
            for (int i = 0; i < 4; ++i)
#pragma unroll
                for (int j = 0; j < 4; ++j)
                    acc[i][j] = __builtin_amdgcn_mfma_f32_16x16x32_bf16(af[i], bfr[j], acc[i][j], 0, 0, 0);
        }
        __syncthreads();
    }

    const float s = expf(scale_log[0]);
    int yrow[4][4]; float mrow[4][4];
    int ycol[4];    float mcol[4];
#pragma unroll
    for (int i = 0; i < 4; ++i)
#pragma unroll
        for (int r = 0; r < 4; ++r) {
            int yy = y[r0 + rw + i * 16 + quad * 4 + r];
            yrow[i][r] = yy; mrow[i][r] = (yy == 0) ? 1.f : 0.f;
        }
#pragma unroll
    for (int j = 0; j < 4; ++j) {
        int yy = y[c0 + cw + j * 16 + l15];
        ycol[j] = yy; mcol[j] = (yy == 0) ? 1.f : 0.f;
    }
    float rZ[4][4] = {}, rF[4][4] = {}, rW[4][4] = {};
    float cZ[4] = {}, cE[4] = {}, cW[4] = {};
    float aAll = 0.f, aC0 = 0.f, aR0 = 0.f, aRC = 0.f;
#pragma unroll
    for (int i = 0; i < 4; ++i)
#pragma unroll
        for (int r = 0; r < 4; ++r) {
            float mr = mrow[i][r];
            int yr = yrow[i][r];
#pragma unroll
            for (int j = 0; j < 4; ++j) {
                float S = acc[i][j][r];
                float L = s * S;
                float e1 = __expf(L);
                float e2 = __expf(S);
                float msk = (yr == ycol[j]) ? 1.f : 0.f;
                rZ[i][r] += e1; rF[i][r] += e1 * L; rW[i][r] += e1 * msk;
                cZ[j] += e2;    cE[j] += e2 * S;    cW[j] += e2 * msk;
                float tmp = S * mcol[j];
                aAll += S; aC0 += tmp; aR0 += S * mr; aRC += tmp * mr;
            }
        }
    // row partials: butterfly over the 16 lanes of each quad; guarded store
    const int p_row = bx * 2 + (cw >> 6);
#pragma unroll
    for (int i = 0; i < 4; ++i)
#pragma unroll
        for (int r = 0; r < 4; ++r) {
#pragma unroll
            for (int m = 1; m < 16; m <<= 1) {
                rZ[i][r] += __shfl_xor(rZ[i][r], m);
                rF[i][r] += __shfl_xor(rF[i][r], m);
                rW[i][r] += __shfl_xor(rW[i][r], m);
            }
            if (l15 == (i * 4 + r)) {
                int grow = r0 + rw + i * 16 + quad * 4 + r;
                int base = ST_ROW + p_row * 4096 + grow;
                st[base]          = rZ[i][r];
                st[base + 262144] = rF[i][r];
                st[base + 524288] = rW[i][r];
            }
        }
    // col partials: reduce across quads
    const int p_col = by * 2 + (rw >> 6);
#pragma unroll
    for (int j = 0; j < 4; ++j) {
        cZ[j] += __shfl_xor(cZ[j], 16); cZ[j] += __shfl_xor(cZ[j], 32);
        cE[j] += __shfl_xor(cE[j], 16); cE[j] += __shfl_xor(cE[j], 32);
        cW[j] += __shfl_xor(cW[j], 16); cW[j] += __shfl_xor(cW[j], 32);
        if (quad == 0) {
            int gcol = c0 + cw + j * 16 + l15;
            int base = ST_COL + p_col * 4096 + gcol;
            st[base]          = cZ[j];
            st[base + 262144] = cE[j];
            st[base + 524288] = cW[j];
        }
    }
    // T scalars: per-wave reduce + store
#pragma unroll
    for (int m = 1; m < 64; m <<= 1) {
        aAll += __shfl_xor(aAll, m); aC0 += __shfl_xor(aC0, m);
        aR0 += __shfl_xor(aR0, m);   aRC += __shfl_xor(aRC, m);
    }
    if (lane == 0) {
        int wg = (by * 32 + bx) * 4 + w;
        float T00 = aRC, T01 = aR0 - aRC, T10 = aC0 - aRC, T11 = aAll - aR0 - aC0 + aRC;
        st[ST_T + wg * 4 + 0] = T00;
        st[ST_T + wg * 4 + 1] = T01;
        st[ST_T + wg * 4 + 2] = T10;
        st[ST_T + wg * 4 + 3] = T11;
    }
}

// ---------------------------------------------------------------------------
// CLIP finalize: one WAVE per row (lane = partial index). grid (1024, 2),
// block = 256 = 4 rows. n0 computed per-block (county folded in).
// Per-row v -> RV (plain store). Block (0,z) reduces T-partials -> TT.
// ---------------------------------------------------------------------------
__global__ __launch_bounds__(256) void clip_finalize(const float* __restrict__ st1,
                                                     const float* __restrict__ st2,
                                                     const int* __restrict__ y,
                                                     float* __restrict__ RV,
                                                     float* __restrict__ TT) {
    __shared__ float cred[256];
    const int z = blockIdx.y;
    const float* st = z ? st2 : st1;
    const int tid = threadIdx.x;
    const int lane = tid & 63;
    const int k = blockIdx.x * 4 + (tid >> 6);
    const float Bf = (float)BSZ;

    float ccnt = 0.f;
    for (int i = tid; i < BSZ; i += 256) ccnt += (y[i] == 0) ? 1.f : 0.f;
    cred[tid] = ccnt;
    __syncthreads();
    for (int ss2 = 128; ss2 > 0; ss2 >>= 1) {
        if (tid < ss2) cred[tid] += cred[tid + ss2];
        __syncthreads();
    }
    const float n0 = cred[0];

    const int base = lane * 4096 + k;
    float Z1 = st[ST_ROW + base];
    float F1 = st[ST_ROW + 262144 + base];
    float W1 = st[ST_ROW + 524288 + base];
    float Z2 = st[ST_COL + base];
    float E2 = st[ST_COL + 262144 + base];
    float W2 = st[ST_COL + 524288 + base];
#pragma unroll
    for (int m = 1; m < 64; m <<= 1) {
        Z1 += __shfl_xor(Z1, m); F1 += __shfl_xor(F1, m); W1 += __shfl_xor(W1, m);
        Z2 += __shfl_xor(Z2, m); E2 += __shfl_xor(E2, m); W2 += __shfl_xor(W2, m);
    }
    if (lane == 0) {
        int yk = y[k];
        float n = (yk == 0) ? n0 : (Bf - n0);
        float a = 1.0f / n;
        float ea = expf(a);
        float denom = n * ea + (Bf - n);
        float q_s = ea / denom, q_d = 1.0f / denom;
        float ld = logf(denom);
        float lq_s = a - ld, lq_d = -ld;
        float Qlq = n * q_s * lq_s + (Bf - n) * q_d * lq_d;
        float term_r = Qlq + F1 / Z1 - lq_d - (lq_s - lq_d) * (W1 / Z1);
        float term_c = Qlq + E2 / Z2 - lq_d - (lq_s - lq_d) * (W2 / Z2);
        RV[(size_t)z * BSZ + k] = (term_r + term_c) / (4.0f * Bf);
    }
    if (blockIdx.x == 0) {
        __shared__ float4 tred[256];
        const float4* tp = (const float4*)&st[ST_T];
        float4 acc = {0.f, 0.f, 0.f, 0.f};
        for (int u = tid; u < 4096; u += 256) {
            float4 t4 = tp[u];
            acc.x += t4.x; acc.y += t4.y; acc.z += t4.z; acc.w += t4.w;
        }
        tred[tid] = acc;
        __syncthreads();
        for (int ss2 = 128; ss2 > 0; ss2 >>= 1) {
            if (tid < ss2) {
                tred[tid].x += tred[tid + ss2].x; tred[tid].y += tred[tid + ss2].y;
                tred[tid].z += tred[tid + ss2].z; tred[tid].w += tred[tid + ss2].w;
            }
            __syncthreads();
        }
        if (tid == 0) {
            TT[z * 4 + 0] = tred[0].x; TT[z * 4 + 1] = tred[0].y;
            TT[z * 4 + 2] = tred[0].z; TT[z * 4 + 3] = tred[0].w;
        }
    }
}

// ---------------------------------------------------------------------------
// gram_splitk: G_mat = X^T X (128x128, K=4096) split-K in 64-row chunks, fp32.
// ||A@B^T||_F^2 = sum (A^T A)∘(B^T B). grid (64, 4). Partials to GP.
// ---------------------------------------------------------------------------
__global__ __launch_bounds__(256) void gram_splitk(const float* __restrict__ isp,
                                                   const float* __restrict__ ish,
                                                   const float* __restrict__ tsp,
                                                   const float* __restrict__ tsh,
                                                   float* __restrict__ GP) {
    __shared__ alignas(16) float As2[64][128];
    const int mat = blockIdx.y, chunk = blockIdx.x;
    const float* A = mat == 0 ? isp : mat == 1 ? ish : mat == 2 ? tsp : tsh;
    const int tid = threadIdx.x;
    const int m0 = chunk * 64;
#pragma unroll
    for (int r = 0; r < 8; ++r) {
        int idx = r * 256 + tid;
        int row = idx >> 5, c4 = (idx & 31) * 4;
        *(float4*)&As2[row][c4] = *(const float4*)&A[(size_t)(m0 + row) * 128 + c4];
    }
    __syncthreads();
    const int ty = tid >> 4, tx = tid & 15;
    float acc[8][8] = {};
    for (int k = 0; k < 64; ++k) {
        float av[8], bv[8];
        *(float4*)&av[0] = *(const float4*)&As2[k][ty * 8];
        *(float4*)&av[4] = *(const float4*)&As2[k][ty * 8 + 4];
        *(float4*)&bv[0] = *(const float4*)&As2[k][tx * 8];
        *(float4*)&bv[4] = *(const float4*)&As2[k][tx * 8 + 4];
#pragma unroll
        for (int i = 0; i < 8; ++i)
#pragma unroll
            for (int j = 0; j < 8; ++j) acc[i][j] += av[i] * bv[j];
    }
    float* Gp = GP + ((size_t)(mat * 64 + chunk) << 14);
#pragma unroll
    for (int i = 0; i < 8; ++i) {
        *(float4*)&Gp[(ty * 8 + i) * 128 + tx * 8]     = *(float4*)&acc[i][0];
        *(float4*)&Gp[(ty * 8 + i) * 128 + tx * 8 + 4] = *(float4*)&acc[i][4];
    }
}

// frob_combine: per entry sum 64 K-partials of each Gram in the pair,
// multiply, reduce -> scal[3+z]. z=0: (ISP,ISH), z=1: (TSP,TSH).
__global__ void frob_combine(const float* __restrict__ GP, float* __restrict__ scal) {
    __shared__ float red[256];
    const int z = blockIdx.y;
    const int tid = threadIdx.x;
    int u = blockIdx.x * 1024 + tid * 4;
    float4 ga = {0.f, 0.f, 0.f, 0.f};
    float4 gb = {0.f, 0.f, 0.f, 0.f};
    const size_t baseA = ((size_t)(2 * z) * 64) << 14;
    const size_t baseB = ((size_t)(2 * z + 1) * 64) << 14;
    for (int c = 0; c < 64; ++c) {
        float4 va = *(const float4*)&GP[baseA + ((size_t)c << 14) + u];
        float4 vb = *(const float4*)&GP[baseB + ((size_t)c << 14) + u];
        ga.x += va.x; ga.y += va.y; ga.z += va.z; ga.w += va.w;
        gb.x += vb.x; gb.y += vb.y; gb.z += vb.z; gb.w += vb.w;
    }
    red[tid] = ga.x * gb.x + ga.y * gb.y + ga.z * gb.z + ga.w * gb.w;
    __syncthreads();
    for (int ss = 128; ss > 0; ss >>= 1) {
        if (tid < ss) red[tid] += red[tid + ss];
        __syncthreads();
    }
    if (tid == 0) atomicAdd(&scal[3 + z], red[0]);
}

// ---------------------------------------------------------------------------
// Scalar heads (z-batched): out[1 + z*BSZ + m] = dot(X[m], w) + b
// ---------------------------------------------------------------------------
__global__ void head4(const float* __restrict__ isp, const float* __restrict__ ish,
                      const float* __restrict__ tsp, const float* __restrict__ tsh,
                      const float* __restrict__ c1w, const float* __restrict__ c2w,
                      const float* __restrict__ c4w, const float* __restrict__ c3w,
                      const float* __restrict__ c1b, const float* __restrict__ c2b,
                      const float* __restrict__ c4b, const float* __restrict__ c3b,
                      float* __restrict__ out) {
    int z = blockIdx.y;
    const float* X = z == 0 ? isp : z == 1 ? ish : z == 2 ? tsp : tsh;
    const float* w = z == 0 ? c1w : z == 1 ? c2w : z == 2 ? c4w : c3w;
    const float* b = z == 0 ? c1b : z == 1 ? c2b : z == 2 ? c4b : c3b;
    int m = blockIdx.x * 256 + threadIdx.x;
    const float4* xp = (const float4*)(X + (size_t)m * 128);
    const float4* wp = (const float4*)w;
    float acc = 0.0f;
#pragma unroll
    for (int u = 0; u < 32; ++u) {
        float4 av = xp[u], cv = wp[u];
        acc += av.x * cv.x + av.y * cv.y + av.z * cv.z + av.w * cv.w;
    }
    out[1 + (size_t)z * BSZ + m] = acc + b[0];
}

// ---------------------------------------------------------------------------
// Final: sum RV per z (+ recount n0) + T tails + gram terms -> out[0]
// ---------------------------------------------------------------------------
__global__ void final_kernel(const float* __restrict__ RV, const float* __restrict__ scal,
                             const int* __restrict__ y,
                             const float* __restrict__ sl1, const float* __restrict__ sl2,
                             float* __restrict__ out) {
    __shared__ float red0[256], red1[256], red2[256];
    int tid = threadIdx.x;
    float s0 = 0.f, s1 = 0.f, cnt = 0.f;
    for (int u = tid; u < BSZ; u += 256) {
        s0 += RV[u]; s1 += RV[BSZ + u];
        cnt += (y[u] == 0) ? 1.f : 0.f;
    }
    red0[tid] = s0; red1[tid] = s1; red2[tid] = cnt;
    __syncthreads();
    for (int ss = 128; ss > 0; ss >>= 1) {
        if (tid < ss) {
            red0[tid] += red0[tid + ss]; red1[tid] += red1[tid + ss];
            red2[tid] += red2[tid + ss];
        }
        __syncthreads();
    }
    if (tid == 0) {
        const float Bf = (float)BSZ;
        float n0 = red2[0], n1 = Bf - n0;
        float e0 = expf(1.f / n0), e1 = expf(1.f / n1);
        float d0 = n0 * e0 + (Bf - n0), d1 = n1 * e1 + (Bf - n1);
        float qs0 = e0 / d0, qd0 = 1.f / d0, qs1 = e1 / d1, qd1 = 1.f / d1;
        float loss_z[2];
        for (int z = 0; z < 2; ++z) {
            float T00 = scal[8 + z * 4 + 0], T01 = scal[8 + z * 4 + 1];
            float T10 = scal[8 + z * 4 + 2], T11 = scal[8 + z * 4 + 3];
            float QS1 = qd0 * (T00 + T01) + (qs0 - qd0) * T00 + qd1 * (T10 + T11) + (qs1 - qd1) * T11;
            float QS2 = qd0 * (T00 + T10) + (qs0 - qd0) * T00 + qd1 * (T01 + T11) + (qs1 - qd1) * T11;
            float s = expf(z ? sl2[0] : sl1[0]);
            loss_z[z] = (z ? red1[0] : red0[0]) + (-s * QS1 - QS2) / (4.0f * Bf);
        }
        float loss_sp = 0.5f * (sqrtf(scal[4]) + sqrtf(scal[3]));
        out[0] = (loss_sp + loss_z[1] + loss_z[0]) / 3.0f;
    }
}

// ---------------------------------------------------------------------------
extern "C" void kernel_launch(void* const* d_in, const int* in_sizes, int n_in,
                              void* d_out, int out_size, void* d_ws, size_t ws_size,
                              hipStream_t stream) {
    const float* i_in  = (const float*)d_in[0];
    const float* t_in  = (const float*)d_in[1];
    const int*   y     = (const int*)d_in[2];
    const float* l1_w  = (const float*)d_in[3];
    const float* l1_b  = (const float*)d_in[4];
    const float* l2_w  = (const float*)d_in[5];
    const float* l2_b  = (const float*)d_in[6];
    const float* l3_w  = (const float*)d_in[7];
    const float* l3_b  = (const float*)d_in[8];
    const float* tl1_w = (const float*)d_in[9];
    const float* tl1_b = (const float*)d_in[10];
    const float* tl2_w = (const float*)d_in[11];
    const float* tl2_b = (const float*)d_in[12];
    const float* isp_w = (const float*)d_in[13];
    const float* isp_b = (const float*)d_in[14];
    const float* ish_w = (const float*)d_in[15];
    const float* ish_b = (const float*)d_in[16];
    const float* tsh_w = (const float*)d_in[17];
    const float* tsh_b = (const float*)d_in[18];
    const float* tsp_w = (const float*)d_in[19];
    const float* tsp_b = (const float*)d_in[20];
    const float* c1_w  = (const float*)d_in[21];
    const float* c1_b  = (const float*)d_in[22];
    const float* c2_w  = (const float*)d_in[23];
    const float* c2_b  = (const float*)d_in[24];
    const float* c3_w  = (const float*)d_in[25];
    const float* c3_b  = (const float*)d_in[26];
    const float* c4_w  = (const float*)d_in[27];
    const float* c4_b  = (const float*)d_in[28];
    const float* scale1 = (const float*)d_in[29];
    const float* scale2 = (const float*)d_in[30];

    float* ws = (float*)d_ws;
    // zeroed fp32 region: SCAL (scal[3],[4] frob atomic targets; [8..15] T sums)
    float* SCAL = ws;                       // 64
    float* RV   = ws + 64;                  // 2*4096 per-row clip terms
    // fp32 work buffers
    float* ISP  = RV + 2 * BSZ;
    float* ISH  = ISP + (size_t)BSZ * 128;
    float* TSP  = ISH + (size_t)BSZ * 128;
    float* TSH  = TSP + (size_t)BSZ * 128;
    // bf16 buffers (IB and WB contiguous -> single cast_all target)
    unsigned short* IB   = (unsigned short*)(TSH + (size_t)BSZ * 128);
    unsigned short* WB   = IB + (size_t)BSZ * 2048;      // 1294336
    unsigned short* FI1B = WB + 1294336;                 // 4096*512
    unsigned short* FI2B = FI1B + (size_t)BSZ * 512;     // 4096*256
    unsigned short* FIB  = FI2B + (size_t)BSZ * 256;     // 4096*128
    unsigned short* FT1B = FIB + (size_t)BSZ * 128;
    unsigned short* FTB  = FT1B + (size_t)BSZ * 128;
    unsigned short* FINB = FTB + (size_t)BSZ * 128;
    unsigned short* FTNB = FINB + (size_t)BSZ * 128;
    unsigned short* ISHN = FTNB + (size_t)BSZ * 128;
    unsigned short* TSHN = ISHN + (size_t)BSZ * 128;
    // ST partial buffers ALIAS IB (16.8 MB): IB fully consumed by the L1
    // mfma_gemm before clip_mfma runs (stream order).
    float* ST1 = (float*)IB;                 // 1589248 floats
    float* ST2 = ST1 + ST_FLOATS;
    // GP aliases the same region: clip_finalize fully consumes ST before
    // gram_splitk runs (stream order).
    float* GP = (float*)IB;

    float* out = (float*)d_out;

    hipMemsetAsync(d_ws, 0, 64 * sizeof(float), stream);
    cast_all<<<9456, 256, 0, stream>>>(i_in, l1_w, l2_w, l3_w, tl2_w, isp_w, ish_w, tsh_w, tsp_w, IB);
    gemm_small<<<dim3(2, 64), dim3(16, 16), 0, stream>>>(t_in, tl1_w, tl1_b, FT1B, BSZ, 128, 49, 1);

    mfma_gemm<<<dim3(4, 32), 256, 0, stream>>>(IB, WB, l1_b, FI1B, nullptr, 512, 2048, 1);
    mfma_gemm<<<dim3(2, 32), 256, 0, stream>>>(FI1B, WB + 1048576, l2_b, FI2B, nullptr, 256, 512, 1);
    gemm34<<<dim3(1, 32, 2), 256, 0, stream>>>(FI2B, FT1B, WB, l3_b, tl2_b, FIB, FTB);
    mfma_heads<<<dim3(1, 32, 4), 256, 0, stream>>>(FIB, FTB, WB + 1228800, WB + 1245184, WB + 1261568,
                                                   WB + 1277952, isp_b, ish_b, tsh_b, tsp_b,
                                                   ISP, ISH, TSH, TSP);
    rownorm4<<<dim3(16, 4), 256, 0, stream>>>(FIB, FTB, ISH, TSH, FINB, FTNB, ISHN, TSHN);

    clip_mfma<<<dim3(32, 32, 2), 256, 0, stream>>>(FINB, FTNB, ISHN, TSHN, y, scale1, scale2, ST1, ST2);
    clip_finalize<<<dim3(1024, 2), 256, 0, stream>>>(ST1, ST2, y, RV, &SCAL[8]);

    gram_splitk<<<dim3(64, 4), 256, 0, stream>>>(ISP, ISH, TSP, TSH, GP);
    frob_combine<<<dim3(16, 2), 256, 0, stream>>>(GP, SCAL);
    head4<<<dim3(16, 4), 256, 0, stream>>>(ISP, ISH, TSP, TSH, c1_w, c2_w, c4_w, c3_w,
                                           c1_b, c2_b, c4_b, c3_b, out);
    final_kernel<<<1, 256, 0, stream>>>(RV, SCAL, y, scale1, scale2, out);
}